// Round 4
// baseline (265.198 us; speedup 1.0000x reference)
//
#include <hip/hip_runtime.h>
#include <cstddef>

#define D 64
#define K 512
#define NROWS (32*64*64)       // 131072 rows
#define RPB 128                // rows per block (vq_main)
#define NBLK (NROWS / RPB)     // 1024 blocks
#define NOUT 8388608           // NROWS * D
#define CHUNK 16               // codes per staged LDS chunk (4 KB)
#define NCHUNK 16              // 256 codes per wave / CHUNK

typedef __attribute__((address_space(1))) const void glb_cvoid;
typedef __attribute__((address_space(3))) void lds_void;

// ws layout (floats):
//   [0,      32768)  : eT[K][D]   transposed codebook
//   [32768,  33280)  : enorm[K]   (np-rounding-exact: sequential non-fused sum)
//   [33280,  34304)  : block partial loss sums [NBLK=1024]

__global__ __launch_bounds__(256) void vq_prep(const float* __restrict__ emb,
                                               float* __restrict__ eT,
                                               float* __restrict__ enorm) {
    const int k = blockIdx.x * blockDim.x + threadIdx.x;
    if (k >= K) return;
    // np.sum(emb*emb, axis=0): axis-0 reduce = sequential row sweep over
    // individually-rounded products. Replicate exactly (no FMA contraction).
    float nrm = 0.f;
#pragma unroll
    for (int d = 0; d < D; ++d) {
        const float v = emb[d * K + k];   // coalesced across k
        nrm = __fadd_rn(nrm, __fmul_rn(v, v));
        eT[k * D + d] = v;
    }
    enorm[k] = nrm;
}

__global__ __launch_bounds__(256, 4) void vq_main(const float* __restrict__ x,
                                                  const float* __restrict__ eT,
                                                  const float* __restrict__ enorm,
                                                  float* __restrict__ out,
                                                  float* __restrict__ partials) {
    // Per-wave private double-buffered codebook staging: 4 waves x 2 bufs x 4KB.
    // global_load_lds => codebook bytes NEVER occupy VGPRs (round-3 post-mortem:
    // in-flight vector loads + pinned xr[64] blew the 128-VGPR cap -> scratch
    // spill of the x-row, VGPR_Count=48, 43% stall time).
    __shared__ float s_ebuf[4][2][CHUNK * D];   // 32 KB
    __shared__ float s_dist[256];
    __shared__ int   s_idx[256];
    __shared__ int   s_code[RPB];
    __shared__ float s_red[4];

    const int t    = threadIdx.x;
    const int wave = t >> 6;
    const int lane = t & 63;
    const int rg   = wave >> 1;                 // row group: 0 -> rows 0..63, 1 -> 64..127
    const int kh   = wave & 1;                  // codebook half
    const size_t rowbase = (size_t)blockIdx.x * RPB;
    const int    rl  = (rg << 6) + lane;        // local row 0..127
    const size_t row = rowbase + rl;

    // ---- load x row into registers (once) ----
    float xr[64];
    const float4* __restrict__ xv = (const float4*)(x + row * D);
#pragma unroll
    for (int j = 0; j < 16; ++j) {
        const float4 v = xv[j];
        xr[4*j+0] = v.x; xr[4*j+1] = v.y; xr[4*j+2] = v.z; xr[4*j+3] = v.w;
    }
#pragma unroll
    for (int j = 0; j < 16; ++j) {
        asm volatile("" : "+v"(xr[4*j+0]), "+v"(xr[4*j+1]),
                          "+v"(xr[4*j+2]), "+v"(xr[4*j+3]));
    }

    // ---- async-stage chunk 0 of this wave's codebook half (overlaps xnorm) ----
    const int kbase = kh << 8;                          // 0 or 256, wave-uniform
    const float* __restrict__ esrc = eT + (size_t)kbase * D;
    float* const edst0 = &s_ebuf[wave][0][0];
    float* const edst1 = &s_ebuf[wave][1][0];

    auto stage = [&](float* dst, int c) {
        // chunk = 16 codes x 64 dims = 4KB contiguous in eT; 4 instrs x (64 lanes x 16B).
        // LDS dest: wave-uniform base (+HW lane*16B); global src per-lane.
        const float* src = esrc + (size_t)c * (CHUNK * D) + (lane << 2);
#pragma unroll
        for (int i = 0; i < 4; ++i) {
            __builtin_amdgcn_global_load_lds((glb_cvoid*)(src + i * 256),
                                             (lds_void*)(dst + i * 256), 16, 0, 0);
        }
    };
    stage(edst0, 0);

    // ---- xnorm: replicate numpy pairwise_sum for n=64 exactly ----
    float r0 = __fmul_rn(xr[0], xr[0]), r1 = __fmul_rn(xr[1], xr[1]);
    float r2 = __fmul_rn(xr[2], xr[2]), r3 = __fmul_rn(xr[3], xr[3]);
    float r4 = __fmul_rn(xr[4], xr[4]), r5 = __fmul_rn(xr[5], xr[5]);
    float r6 = __fmul_rn(xr[6], xr[6]), r7 = __fmul_rn(xr[7], xr[7]);
#pragma unroll
    for (int b = 1; b < 8; ++b) {
        r0 = __fadd_rn(r0, __fmul_rn(xr[8*b+0], xr[8*b+0]));
        r1 = __fadd_rn(r1, __fmul_rn(xr[8*b+1], xr[8*b+1]));
        r2 = __fadd_rn(r2, __fmul_rn(xr[8*b+2], xr[8*b+2]));
        r3 = __fadd_rn(r3, __fmul_rn(xr[8*b+3], xr[8*b+3]));
        r4 = __fadd_rn(r4, __fmul_rn(xr[8*b+4], xr[8*b+4]));
        r5 = __fadd_rn(r5, __fmul_rn(xr[8*b+5], xr[8*b+5]));
        r6 = __fadd_rn(r6, __fmul_rn(xr[8*b+6], xr[8*b+6]));
        r7 = __fadd_rn(r7, __fmul_rn(xr[8*b+7], xr[8*b+7]));
    }
    const float xnorm = __fadd_rn(__fadd_rn(__fadd_rn(r0, r1), __fadd_rn(r2, r3)),
                                  __fadd_rn(__fadd_rn(r4, r5), __fadd_rn(r6, r7)));

    // ---- scan this wave's codebook half: 16 chunks, double-buffered, no barriers ----
    // d_k = fl( fl(xnorm - fl(2*dot_k)) + enorm_k ) — same rounding as verified r2/r3.
    float best = 3.4028235e38f;
    int   bidx = 0;
#pragma unroll 1
    for (int c = 0; c < NCHUNK; ++c) {
        const float* eb = (c & 1) ? edst1 : edst0;
        if (c + 1 < NCHUNK) {
            stage((c & 1) ? edst0 : edst1, c + 1);
            // counted wait: the 4 just-issued stage(c+1) ops may stay in flight;
            // everything older (incl. stage(c)) is drained. vmem retires in order,
            // so extra compiler-issued loads only make this conservative.
            asm volatile("s_waitcnt vmcnt(4)" ::: "memory");
        } else {
            asm volatile("s_waitcnt vmcnt(0)" ::: "memory");
        }
        __builtin_amdgcn_sched_barrier(0);
        const int kc = kbase + c * CHUNK;
#pragma unroll 1
        for (int g = 0; g < CHUNK / 2; ++g) {
            const float4* __restrict__ e0 = (const float4*)(eb + (2*g+0) * D);
            const float4* __restrict__ e1 = (const float4*)(eb + (2*g+1) * D);
            // per code: 4 chains x 16 deep + ((c0+c1)+(c2+c3)) tree — identical
            // rounding to the bit-exact round-2/3 kernels. e-reads are LDS
            // broadcasts (same addr across lanes -> conflict-free).
            float a00 = 0.f, a01 = 0.f, a02 = 0.f, a03 = 0.f;
            float a10 = 0.f, a11 = 0.f, a12 = 0.f, a13 = 0.f;
#pragma unroll
            for (int j = 0; j < 16; ++j) {
                const float4 v0 = e0[j], v1 = e1[j];
                const float x0 = xr[4*j+0], x1 = xr[4*j+1];
                const float x2 = xr[4*j+2], x3 = xr[4*j+3];
                a00 = fmaf(x0, v0.x, a00); a10 = fmaf(x0, v1.x, a10);
                a01 = fmaf(x1, v0.y, a01); a11 = fmaf(x1, v1.y, a11);
                a02 = fmaf(x2, v0.z, a02); a12 = fmaf(x2, v1.z, a12);
                a03 = fmaf(x3, v0.w, a03); a13 = fmaf(x3, v1.w, a13);
            }
            const float dot0 = __fadd_rn(__fadd_rn(a00, a01), __fadd_rn(a02, a03));
            const float dot1 = __fadd_rn(__fadd_rn(a10, a11), __fadd_rn(a12, a13));
            const float d0 = __fadd_rn(__fsub_rn(xnorm, __fmul_rn(2.f, dot0)), enorm[kc + 2*g + 0]);
            const float d1 = __fadd_rn(__fsub_rn(xnorm, __fmul_rn(2.f, dot1)), enorm[kc + 2*g + 1]);
            // ascending scan + strict < keeps the FIRST minimum (np.argmin tie-break)
            if (d0 < best) { best = d0; bidx = kc + 2*g + 0; }
            if (d1 < best) { best = d1; bidx = kc + 2*g + 1; }
        }
    }

    // ---- combine the two K-halves per row ----
    s_dist[t] = best;
    s_idx[t]  = bidx;
    __syncthreads();
    if (t < RPB) {
        // row r: half-0 result at thread ((r>>6)<<7)+(r&63), half-1 at +64
        const int t0 = ((t >> 6) << 7) + (t & 63);
        float b0 = s_dist[t0];      int i0 = s_idx[t0];
        const float b1 = s_dist[t0 + 64]; const int i1 = s_idx[t0 + 64];
        if (b1 < b0) { b0 = b1; i0 = i1; }   // strict: lower-k half wins ties
        s_code[t] = i0;
    }
    __syncthreads();

    // ---- coalesced transpose epilogue (16 lanes per row, contiguous float4) ----
    const int cch = t & 15;      // float4 chunk within row
    const int r0i = t >> 4;      // base row 0..15
    float lacc = 0.f;
#pragma unroll
    for (int i = 0; i < 8; ++i) {
        const int r = r0i + 16 * i;
        const int code = s_code[r];
        const float4 q = *(const float4*)(eT + (size_t)code * D + 4 * cch);
        const float4 b = *(const float4*)(x + (rowbase + r) * D + 4 * cch);  // L1/L2-hot
        const float f0 = __fsub_rn(b.x, q.x), f1 = __fsub_rn(b.y, q.y);
        const float f2 = __fsub_rn(b.z, q.z), f3 = __fsub_rn(b.w, q.w);
        lacc = fmaf(f0, f0, lacc); lacc = fmaf(f1, f1, lacc);
        lacc = fmaf(f2, f2, lacc); lacc = fmaf(f3, f3, lacc);
        float4 o;
        o.x = __fadd_rn(b.x, __fsub_rn(q.x, b.x));
        o.y = __fadd_rn(b.y, __fsub_rn(q.y, b.y));
        o.z = __fadd_rn(b.z, __fsub_rn(q.z, b.z));
        o.w = __fadd_rn(b.w, __fsub_rn(q.w, b.w));
        *(float4*)(out + (rowbase + r) * D + 4 * cch) = o;
    }

    // ---- block loss reduction ----
#pragma unroll
    for (int off = 32; off > 0; off >>= 1) lacc += __shfl_down(lacc, off);
    if (lane == 0) s_red[wave] = lacc;
    __syncthreads();
    if (t == 0) partials[blockIdx.x] = (s_red[0] + s_red[1]) + (s_red[2] + s_red[3]);
}

__global__ __launch_bounds__(256) void vq_finish(const float* __restrict__ partials,
                                                 float* __restrict__ loss_out) {
    __shared__ float s_red[4];
    const int t = threadIdx.x;
    float a = 0.f;
#pragma unroll
    for (int i = 0; i < 4; ++i) a += partials[t + 256 * i];   // NBLK=1024
#pragma unroll
    for (int off = 32; off > 0; off >>= 1) a += __shfl_down(a, off);
    if ((t & 63) == 0) s_red[t >> 6] = a;
    __syncthreads();
    if (t == 0) {
        const float S = (s_red[0] + s_red[1]) + (s_red[2] + s_red[3]);
        const float m = S / (float)NOUT;
        loss_out[0] = m + 0.25f * m;   // mean + BETA*mean
    }
}

extern "C" void kernel_launch(void* const* d_in, const int* in_sizes, int n_in,
                              void* d_out, int out_size, void* d_ws, size_t ws_size,
                              hipStream_t stream) {
    const float* x   = (const float*)d_in[0];
    const float* emb = (const float*)d_in[1];
    float* out = (float*)d_out;
    float* ws  = (float*)d_ws;

    float* eT       = ws;
    float* enorm    = ws + 32768;
    float* partials = ws + 32768 + 512;

    vq_prep<<<2, 256, 0, stream>>>(emb, eT, enorm);
    vq_main<<<NBLK, 256, 0, stream>>>(x, eT, enorm, out, partials);
    vq_finish<<<1, 256, 0, stream>>>(partials, out + NOUT);
}

// Round 5
// 218.719 us; speedup vs baseline: 1.2125x; 1.2125x over previous
//
#include <hip/hip_runtime.h>
#include <cstddef>

#define D 64
#define K 512
#define NROWS (32*64*64)       // 131072 rows
#define RPB 64                 // rows per block (vq_main)
#define NBLK (NROWS / RPB)     // 2048 blocks
#define NOUT 8388608           // NROWS * D

// ws layout (floats):
//   [0,      32768)  : eT[K][D]   transposed codebook
//   [32768,  33280)  : enorm[K]   (np-rounding-exact: sequential non-fused sum)
//   [33280,  35328)  : block partial loss sums [NBLK=2048]

__global__ __launch_bounds__(256) void vq_prep(const float* __restrict__ emb,
                                               float* __restrict__ eT,
                                               float* __restrict__ enorm) {
    const int k = blockIdx.x * blockDim.x + threadIdx.x;
    if (k >= K) return;
    // np.sum(emb*emb, axis=0): axis-0 reduce = sequential row sweep over
    // individually-rounded products. Replicate exactly (no FMA contraction).
    float nrm = 0.f;
#pragma unroll
    for (int d = 0; d < D; ++d) {
        const float v = emb[d * K + k];   // coalesced across k
        nrm = __fadd_rn(nrm, __fmul_rn(v, v));
        eT[k * D + d] = v;
    }
    enorm[k] = nrm;
}

// amdgpu_waves_per_eu(2,4): r2-r4 post-mortem — the backend's occupancy
// heuristic squeezed VGPR allocation to 48-64 regs (8 waves/EU target),
// spilling the pinned xr[64] row to scratch every round; launch_bounds'
// 128-VGPR cap did NOT relax it. min=2 waves/EU raises the budget to 256
// VGPRs, so the ~112 live values fit with zero spill; resulting occupancy
// (512/~112 = 4 waves/SIMD = 50%) matches what r3 actually achieved anyway.
__global__ __launch_bounds__(256) __attribute__((amdgpu_waves_per_eu(2, 4)))
void vq_main(const float* __restrict__ x,
             const float* __restrict__ eT,
             const float* __restrict__ enorm,
             float* __restrict__ out,
             float* __restrict__ partials) {
    __shared__ float s_dist[256];
    __shared__ int   s_idx[256];
    __shared__ int   s_code[RPB];
    __shared__ float s_red[4];

    const int t    = threadIdx.x;
    const int wave = t >> 6;
    const int lane = t & 63;                    // = local row for the scan phase
    const size_t rowbase = (size_t)blockIdx.x * RPB;
    const size_t row = rowbase + lane;

    // ---- load x row into registers (once) ----
    float xr[64];
    const float4* __restrict__ xv = (const float4*)(x + row * D);
#pragma unroll
    for (int j = 0; j < 16; ++j) {
        const float4 v = xv[j];
        xr[4*j+0] = v.x; xr[4*j+1] = v.y; xr[4*j+2] = v.z; xr[4*j+3] = v.w;
    }
    // Pin the row in VGPRs: an asm-defined value cannot be rematerialized from
    // its global load, so with the relaxed VGPR budget the row stays resident.
#pragma unroll
    for (int j = 0; j < 16; ++j) {
        asm volatile("" : "+v"(xr[4*j+0]), "+v"(xr[4*j+1]),
                          "+v"(xr[4*j+2]), "+v"(xr[4*j+3]));
    }

    // ---- xnorm: replicate numpy pairwise_sum for n=64 exactly ----
    float r0 = __fmul_rn(xr[0], xr[0]), r1 = __fmul_rn(xr[1], xr[1]);
    float r2 = __fmul_rn(xr[2], xr[2]), r3 = __fmul_rn(xr[3], xr[3]);
    float r4 = __fmul_rn(xr[4], xr[4]), r5 = __fmul_rn(xr[5], xr[5]);
    float r6 = __fmul_rn(xr[6], xr[6]), r7 = __fmul_rn(xr[7], xr[7]);
#pragma unroll
    for (int b = 1; b < 8; ++b) {
        r0 = __fadd_rn(r0, __fmul_rn(xr[8*b+0], xr[8*b+0]));
        r1 = __fadd_rn(r1, __fmul_rn(xr[8*b+1], xr[8*b+1]));
        r2 = __fadd_rn(r2, __fmul_rn(xr[8*b+2], xr[8*b+2]));
        r3 = __fadd_rn(r3, __fmul_rn(xr[8*b+3], xr[8*b+3]));
        r4 = __fadd_rn(r4, __fmul_rn(xr[8*b+4], xr[8*b+4]));
        r5 = __fadd_rn(r5, __fmul_rn(xr[8*b+5], xr[8*b+5]));
        r6 = __fadd_rn(r6, __fmul_rn(xr[8*b+6], xr[8*b+6]));
        r7 = __fadd_rn(r7, __fmul_rn(xr[8*b+7], xr[8*b+7]));
    }
    const float xnorm = __fadd_rn(__fadd_rn(__fadd_rn(r0, r1), __fadd_rn(r2, r3)),
                                  __fadd_rn(__fadd_rn(r4, r5), __fadd_rn(r6, r7)));

    // ---- scan this wave's QUARTER of the codebook (128 codes) ----
    // d_k = fl( fl(xnorm - fl(2*dot_k)) + enorm_k )  — np's exact rounding order.
    // Codebook address is wave-uniform -> s_load/SGPR-broadcast path (r2/r3
    // evidence: SGPR=96-112), costing no VALU or LDS issue slots.
    const int kbase = __builtin_amdgcn_readfirstlane(wave << 7);  // wave*128
    float best = 3.4028235e38f;
    int   bidx = 0;
    for (int kk = 0; kk < 128; kk += 4) {
        const float4* __restrict__ e0 = (const float4*)(eT + (size_t)(kbase + kk + 0) * D);
        const float4* __restrict__ e1 = (const float4*)(eT + (size_t)(kbase + kk + 1) * D);
        const float4* __restrict__ e2 = (const float4*)(eT + (size_t)(kbase + kk + 2) * D);
        const float4* __restrict__ e3 = (const float4*)(eT + (size_t)(kbase + kk + 3) * D);
        // 16 independent fma chains (4 codes x 4 components), each 16 deep:
        // identical rounding structure to the bit-exact round-2/3 kernels.
        float a00 = 0.f, a01 = 0.f, a02 = 0.f, a03 = 0.f;
        float a10 = 0.f, a11 = 0.f, a12 = 0.f, a13 = 0.f;
        float a20 = 0.f, a21 = 0.f, a22 = 0.f, a23 = 0.f;
        float a30 = 0.f, a31 = 0.f, a32 = 0.f, a33 = 0.f;
#pragma unroll
        for (int j = 0; j < 16; ++j) {
            const float4 v0 = e0[j], v1 = e1[j], v2 = e2[j], v3 = e3[j];
            const float x0 = xr[4*j+0], x1 = xr[4*j+1], x2 = xr[4*j+2], x3 = xr[4*j+3];
            a00 = fmaf(x0, v0.x, a00); a10 = fmaf(x0, v1.x, a10); a20 = fmaf(x0, v2.x, a20); a30 = fmaf(x0, v3.x, a30);
            a01 = fmaf(x1, v0.y, a01); a11 = fmaf(x1, v1.y, a11); a21 = fmaf(x1, v2.y, a21); a31 = fmaf(x1, v3.y, a31);
            a02 = fmaf(x2, v0.z, a02); a12 = fmaf(x2, v1.z, a12); a22 = fmaf(x2, v2.z, a22); a32 = fmaf(x2, v3.z, a32);
            a03 = fmaf(x3, v0.w, a03); a13 = fmaf(x3, v1.w, a13); a23 = fmaf(x3, v2.w, a23); a33 = fmaf(x3, v3.w, a33);
        }
        const float dot0 = __fadd_rn(__fadd_rn(a00, a01), __fadd_rn(a02, a03));
        const float dot1 = __fadd_rn(__fadd_rn(a10, a11), __fadd_rn(a12, a13));
        const float dot2 = __fadd_rn(__fadd_rn(a20, a21), __fadd_rn(a22, a23));
        const float dot3 = __fadd_rn(__fadd_rn(a30, a31), __fadd_rn(a32, a33));
        const float d0 = __fadd_rn(__fsub_rn(xnorm, __fmul_rn(2.f, dot0)), enorm[kbase + kk + 0]);
        const float d1 = __fadd_rn(__fsub_rn(xnorm, __fmul_rn(2.f, dot1)), enorm[kbase + kk + 1]);
        const float d2 = __fadd_rn(__fsub_rn(xnorm, __fmul_rn(2.f, dot2)), enorm[kbase + kk + 2]);
        const float d3 = __fadd_rn(__fsub_rn(xnorm, __fmul_rn(2.f, dot3)), enorm[kbase + kk + 3]);
        // ascending scan + strict < keeps the FIRST minimum (np.argmin tie-break)
        if (d0 < best) { best = d0; bidx = kbase + kk + 0; }
        if (d1 < best) { best = d1; bidx = kbase + kk + 1; }
        if (d2 < best) { best = d2; bidx = kbase + kk + 2; }
        if (d3 < best) { best = d3; bidx = kbase + kk + 3; }
    }

    // ---- combine the 4 K-quarters per row ----
    s_dist[t] = best;
    s_idx[t]  = bidx;
    __syncthreads();
    if (t < RPB) {
        float bb = s_dist[t];
        int   bi = s_idx[t];
#pragma unroll
        for (int w = 1; w < 4; ++w) {
            const float ob = s_dist[w * 64 + t];
            const int   oi = s_idx[w * 64 + t];
            // quarters visited in ascending-k order; strict < keeps lowest k on ties
            if (ob < bb) { bb = ob; bi = oi; }
        }
        s_code[t] = bi;
    }
    __syncthreads();

    // ---- coalesced transpose epilogue ----
    // 16 lanes cover one row (16 x float4 = 256B); consecutive threads write
    // consecutive 16B chunks -> fully coalesced 1KB/wave stores.
    const int c  = t & 15;      // float4 chunk within row
    const int r0i = t >> 4;     // base row 0..15
    float lacc = 0.f;
#pragma unroll
    for (int i = 0; i < 4; ++i) {
        const int r = r0i + 16 * i;
        const int code = s_code[r];
        const float4 q = *(const float4*)(eT + (size_t)code * D + 4 * c);
        const float4 b = *(const float4*)(x + (rowbase + r) * D + 4 * c);  // L1/L2-hot re-read
        const float f0 = __fsub_rn(b.x, q.x), f1 = __fsub_rn(b.y, q.y);
        const float f2 = __fsub_rn(b.z, q.z), f3 = __fsub_rn(b.w, q.w);
        lacc = fmaf(f0, f0, lacc); lacc = fmaf(f1, f1, lacc);
        lacc = fmaf(f2, f2, lacc); lacc = fmaf(f3, f3, lacc);
        float4 o;
        o.x = __fadd_rn(b.x, __fsub_rn(q.x, b.x));
        o.y = __fadd_rn(b.y, __fsub_rn(q.y, b.y));
        o.z = __fadd_rn(b.z, __fsub_rn(q.z, b.z));
        o.w = __fadd_rn(b.w, __fsub_rn(q.w, b.w));
        *(float4*)(out + (rowbase + r) * D + 4 * c) = o;
    }

    // ---- block loss reduction ----
#pragma unroll
    for (int off = 32; off > 0; off >>= 1) lacc += __shfl_down(lacc, off);
    if (lane == 0) s_red[wave] = lacc;
    __syncthreads();
    if (t == 0) partials[blockIdx.x] = (s_red[0] + s_red[1]) + (s_red[2] + s_red[3]);
}

__global__ __launch_bounds__(256) void vq_finish(const float* __restrict__ partials,
                                                 float* __restrict__ loss_out) {
    __shared__ float s_red[4];
    const int t = threadIdx.x;
    float a = 0.f;
#pragma unroll
    for (int i = 0; i < 8; ++i) a += partials[t + 256 * i];   // NBLK=2048
#pragma unroll
    for (int off = 32; off > 0; off >>= 1) a += __shfl_down(a, off);
    if ((t & 63) == 0) s_red[t >> 6] = a;
    __syncthreads();
    if (t == 0) {
        const float S = (s_red[0] + s_red[1]) + (s_red[2] + s_red[3]);
        const float m = S / (float)NOUT;
        loss_out[0] = m + 0.25f * m;   // mean + BETA*mean
    }
}

extern "C" void kernel_launch(void* const* d_in, const int* in_sizes, int n_in,
                              void* d_out, int out_size, void* d_ws, size_t ws_size,
                              hipStream_t stream) {
    const float* x   = (const float*)d_in[0];
    const float* emb = (const float*)d_in[1];
    float* out = (float*)d_out;
    float* ws  = (float*)d_ws;

    float* eT       = ws;
    float* enorm    = ws + 32768;
    float* partials = ws + 32768 + 512;

    vq_prep<<<2, 256, 0, stream>>>(emb, eT, enorm);
    vq_main<<<NBLK, 256, 0, stream>>>(x, eT, enorm, out, partials);
    vq_finish<<<1, 256, 0, stream>>>(partials, out + NOUT);
}